// Round 1
// baseline (662.729 us; speedup 1.0000x reference)
//
#include <hip/hip_runtime.h>
#include <hip/hip_bf16.h>
#include <math.h>

#define B_SZ 64
#define NQ   512
#define NV   1024
#define QD   768
#define VD   512
#define HIDD 512

typedef __bf16 bf16x8 __attribute__((ext_vector_type(8)));
typedef __bf16 bf16x4 __attribute__((ext_vector_type(4)));
typedef float  floatx4 __attribute__((ext_vector_type(4)));

// async global->LDS, 16 bytes per lane; LDS dest is wave-uniform base,
// HW writes lane l at base + l*16 (linear). Swizzle must be applied on the
// global SOURCE address + the LDS READ (both-sides-or-neither).
__device__ __forceinline__ void g2lds16(const __bf16* g, __bf16* l) {
    __builtin_amdgcn_global_load_lds((const __attribute__((address_space(1))) void*)g,
                                     (__attribute__((address_space(3))) void*)l,
                                     16, 0, 0);
}

// exp(tanh(s)) = e^(1 - 2/(e^{2s}+1)); saturates correctly as e^{2s}->0/inf.
__device__ __forceinline__ float exptanh(float s) {
    float t = __expf(2.0f * s);
    float r = __builtin_amdgcn_rcpf(t + 1.0f);
    return __expf(1.0f - 2.0f * r);
}

// ---------------------------------------------------------------------------
// fp32 -> bf16 convert for both weight matrices in one launch (dests adjacent).
__global__ __launch_bounds__(256) void cvt2_k(const float* __restrict__ s0,
                                              const float* __restrict__ s1,
                                              __bf16* __restrict__ d,
                                              int n4a, int n4tot) {
    int i = blockIdx.x * 256 + threadIdx.x;
    if (i >= n4tot) return;
    const float* s = (i < n4a) ? (s0 + (size_t)i * 4) : (s1 + (size_t)(i - n4a) * 4);
    float4 f = *(const float4*)s;
    bf16x4 o;
    o[0] = (__bf16)f.x; o[1] = (__bf16)f.y; o[2] = (__bf16)f.z; o[3] = (__bf16)f.w;
    *(bf16x4*)(d + (size_t)i * 4) = o;
}

// ---------------------------------------------------------------------------
// Projection GEMM, Q and V fused into one dispatch (blocks < nqblk do Q).
// Block = 64 rows x ALL 512 cols (A read from HBM exactly once). 4 waves,
// each 64x128 (acc 4x8). Double-buffered LDS, 2-phase schedule: stage k+1
// (g2lds for W, reg-staged fp32->bf16 convert for A) overlapped with
// compute of k. XOR swizzle slot^=(row>>1)&3 kills the 8-way bank conflict.
__global__ __launch_bounds__(256, 2) void proj_k(
    const float* __restrict__ Qin, const float* __restrict__ Vin,
    const __bf16* __restrict__ Wqb, const __bf16* __restrict__ Wvb,
    const float* __restrict__ bq, const float* __restrict__ bv,
    __bf16* __restrict__ Qp, __bf16* __restrict__ Vp)
{
    __shared__ __bf16 As[2][64 * 32];    // 8 KB
    __shared__ __bf16 Bs[2][512 * 32];   // 64 KB
    const int nqblk = (B_SZ * NQ) / 64;
    const float* A; const __bf16* W; const float* bias; __bf16* Cout; int K, mblk;
    if ((int)blockIdx.x < nqblk) {
        A = Qin; W = Wqb; bias = bq; Cout = Qp; K = QD; mblk = blockIdx.x;
    } else {
        A = Vin; W = Wvb; bias = bv; Cout = Vp; K = VD; mblk = blockIdx.x - nqblk;
    }

    const int t = threadIdx.x, lane = t & 63, wave = t >> 6;
    const int fr = lane & 15, quad = lane >> 4;
    const int fo   = (quad ^ ((fr >> 1) & 3)) * 8;            // swizzled frag read
    const int gksw = ((lane & 3) ^ ((lane >> 3) & 3)) * 8;    // pre-swizzled g2lds src col
    const int tile_m = mblk * 64;
    const int wn = wave * 128;

    // W staging: 8 g2lds calls, call c covers rows c*64 + wave*16 + (lane>>2)
    const __bf16* wsrc = W + (size_t)(wave * 16 + (lane >> 2)) * K + gksw;
    // A staging: thread t handles row t>>2, source slot t&3 (8 fp32 elems)
    const int arow = t >> 2, aslot = t & 3;
    const float* ap = A + (size_t)(tile_m + arow) * K + aslot * 8;
    const int awoff = arow * 32 + ((aslot ^ ((arow >> 1) & 3)) * 8);  // swizzled write

    floatx4 acc[4][8] = {};

    auto stage_w = [&](int p, int k0) {
        #pragma unroll
        for (int c = 0; c < 8; c++)
            g2lds16(wsrc + (size_t)(c * 64) * K + k0, &Bs[p][(c * 64 + wave * 16) * 32]);
    };
    auto cvt_a = [&](int p, float4 f0, float4 f1) {
        bf16x8 pk;
        pk[0] = (__bf16)f0.x; pk[1] = (__bf16)f0.y; pk[2] = (__bf16)f0.z; pk[3] = (__bf16)f0.w;
        pk[4] = (__bf16)f1.x; pk[5] = (__bf16)f1.y; pk[6] = (__bf16)f1.z; pk[7] = (__bf16)f1.w;
        *(bf16x8*)&As[p][awoff] = pk;
    };
    auto compute = [&](int p) {
        bf16x8 af[4];
        #pragma unroll
        for (int i = 0; i < 4; i++)
            af[i] = *(const bf16x8*)&As[p][(16 * i + fr) * 32 + fo];
        #pragma unroll
        for (int j = 0; j < 8; j++) {
            bf16x8 bg = *(const bf16x8*)&Bs[p][(wn + 16 * j + fr) * 32 + fo];
            #pragma unroll
            for (int i = 0; i < 4; i++)
                acc[i][j] = __builtin_amdgcn_mfma_f32_16x16x32_bf16(af[i], bg, acc[i][j], 0, 0, 0);
        }
    };

    // prologue: stage tile 0
    {
        float4 f0 = *(const float4*)(ap);
        float4 f1 = *(const float4*)(ap + 4);
        stage_w(0, 0);
        cvt_a(0, f0, f1);
    }
    __syncthreads();
    int cur = 0;
    for (int k0 = 32; k0 < K; k0 += 32) {
        float4 f0 = *(const float4*)(ap + k0);       // A prefetch (global->reg)
        float4 f1 = *(const float4*)(ap + k0 + 4);
        const int nxt = cur ^ 1;
        stage_w(nxt, k0);                            // in flight across compute
        compute(cur);
        cvt_a(nxt, f0, f1);
        __syncthreads();                             // drains vm+lgkm once per step
        cur = nxt;
    }
    compute(cur);

    #pragma unroll
    for (int j = 0; j < 8; j++) {
        const int col = wn + 16 * j + fr;
        const float bvv = bias[col];
        #pragma unroll
        for (int i = 0; i < 4; i++)
            #pragma unroll
            for (int r = 0; r < 4; r++) {
                const int row = tile_m + 16 * i + quad * 4 + r;
                Cout[(size_t)row * HIDD + col] = (__bf16)(acc[i][j][r] + bvv);
            }
    }
}

// ---------------------------------------------------------------------------
// Per batch: S = Qp[b] @ Vp[b]^T on a 128x256 tile; E = exp(tanh(S)) -> bf16;
// row sums -> R, col sums -> C (atomics). 4 waves, each 64x128 (acc 4x8,
// 12 ds_read per 32 MFMA). Double-buffered 2-phase + XOR swizzle as above.
__global__ __launch_bounds__(256, 2) void gemm_h(
    const __bf16* __restrict__ Qp, const __bf16* __restrict__ Vp,
    __bf16* __restrict__ Eg, float* __restrict__ R, float* __restrict__ Csum)
{
    __shared__ __bf16 As[2][128 * 32];   // 16 KB
    __shared__ __bf16 Bs[2][256 * 32];   // 32 KB
    const int b      = blockIdx.z;
    const int tile_q = blockIdx.y * 128;
    const int tile_v = blockIdx.x * 256;
    const int t = threadIdx.x, lane = t & 63, wave = t >> 6;
    const int fr = lane & 15, quad = lane >> 4;
    const int fo   = (quad ^ ((fr >> 1) & 3)) * 8;
    const int gksw = ((lane & 3) ^ ((lane >> 3) & 3)) * 8;
    const int wm = (wave >> 1) * 64, wn = (wave & 1) * 128;

    const __bf16* Aq = Qp + ((size_t)b * NQ + tile_q + wave * 16 + (lane >> 2)) * HIDD + gksw;
    const __bf16* Bv = Vp + ((size_t)b * NV + tile_v + wave * 16 + (lane >> 2)) * HIDD + gksw;

    auto stage = [&](int p, int k0) {
        #pragma unroll
        for (int c = 0; c < 2; c++)
            g2lds16(Aq + (size_t)(c * 64) * HIDD + k0, &As[p][(c * 64 + wave * 16) * 32]);
        #pragma unroll
        for (int c = 0; c < 4; c++)
            g2lds16(Bv + (size_t)(c * 64) * HIDD + k0, &Bs[p][(c * 64 + wave * 16) * 32]);
    };

    floatx4 acc[4][8] = {};
    auto compute = [&](int p) {
        bf16x8 af[4];
        #pragma unroll
        for (int i = 0; i < 4; i++)
            af[i] = *(const bf16x8*)&As[p][(wm + 16 * i + fr) * 32 + fo];
        #pragma unroll
        for (int j = 0; j < 8; j++) {
            bf16x8 bg = *(const bf16x8*)&Bs[p][(wn + 16 * j + fr) * 32 + fo];
            #pragma unroll
            for (int i = 0; i < 4; i++)
                acc[i][j] = __builtin_amdgcn_mfma_f32_16x16x32_bf16(af[i], bg, acc[i][j], 0, 0, 0);
        }
    };

    stage(0, 0);
    __syncthreads();
    int cur = 0;
    for (int k0 = 32; k0 < HIDD; k0 += 32) {
        stage(cur ^ 1, k0);
        compute(cur);
        __syncthreads();
        cur ^= 1;
    }
    compute(cur);

    #pragma unroll
    for (int i = 0; i < 4; i++)
        #pragma unroll
        for (int j = 0; j < 8; j++)
            #pragma unroll
            for (int r = 0; r < 4; r++)
                acc[i][j][r] = exptanh(acc[i][j][r]);

    #pragma unroll
    for (int i = 0; i < 4; i++)
        #pragma unroll
        for (int r = 0; r < 4; r++) {
            const size_t rowbase =
                ((size_t)b * NQ + tile_q + wm + 16 * i + quad * 4 + r) * NV + tile_v;
            #pragma unroll
            for (int j = 0; j < 8; j++)
                Eg[rowbase + wn + 16 * j + fr] = (__bf16)acc[i][j][r];
        }

    // row sums over this wave's 128 cols -> R (reduce over fr)
    #pragma unroll
    for (int i = 0; i < 4; i++)
        #pragma unroll
        for (int r = 0; r < 4; r++) {
            float s = 0.f;
            #pragma unroll
            for (int j = 0; j < 8; j++) s += acc[i][j][r];
            s += __shfl_xor(s, 1); s += __shfl_xor(s, 2);
            s += __shfl_xor(s, 4); s += __shfl_xor(s, 8);
            if (fr == 0)
                atomicAdd(&R[b * NQ + tile_q + wm + 16 * i + quad * 4 + r], s);
        }
    // col sums over this wave's 64 rows -> C (reduce over quad)
    #pragma unroll
    for (int j = 0; j < 8; j++) {
        float s = 0.f;
        #pragma unroll
        for (int i = 0; i < 4; i++)
            #pragma unroll
            for (int r = 0; r < 4; r++) s += acc[i][j][r];
        s += __shfl_xor(s, 16); s += __shfl_xor(s, 32);
        if (quad == 0)
            atomicAdd(&Csum[b * NV + tile_v + wn + 16 * j + fr], s);
    }
}

// ---------------------------------------------------------------------------
// One E pass computes both marginals:
//   sv[b,v] = sum_q E[b,q,v]/R[b,q]   (atomic partials)
//   sq[b,q] = sum_v E[b,q,v]/C[b,v]   (wave-exclusive rows, direct write)
// 16 rows/block (4/wave) for TLP.
__global__ __launch_bounds__(256) void marg_k(
    const __bf16* __restrict__ E, const float* __restrict__ R,
    const float* __restrict__ C, float* __restrict__ sv,
    float* __restrict__ sq)
{
    const int b  = blockIdx.y;
    const int q0 = blockIdx.x * 16;
    const int t = threadIdx.x, lane = t & 63, wave = t >> 6;
    const float* Cb = C + b * NV;
    float ci[2][8];
    float svp[2][8] = {};
    #pragma unroll
    for (int c = 0; c < 2; c++) {
        float4 c0 = *(const float4*)&Cb[c * 512 + lane * 8];
        float4 c1 = *(const float4*)&Cb[c * 512 + lane * 8 + 4];
        ci[c][0] = 1.0f / c0.x; ci[c][1] = 1.0f / c0.y;
        ci[c][2] = 1.0f / c0.z; ci[c][3] = 1.0f / c0.w;
        ci[c][4] = 1.0f / c1.x; ci[c][5] = 1.0f / c1.y;
        ci[c][6] = 1.0f / c1.z; ci[c][7] = 1.0f / c1.w;
    }
    const float* Rb = R + b * NQ + q0;
    #pragma unroll
    for (int rr = 0; rr < 4; rr++) {
        const int q = wave * 4 + rr;
        const __bf16* Erow = E + ((size_t)b * NQ + q0 + q) * NV;
        const float ri = 1.0f / Rb[q];
        float p = 0.f;
        #pragma unroll
        for (int c = 0; c < 2; c++) {
            bf16x8 ev = *(const bf16x8*)&Erow[c * 512 + lane * 8];
            #pragma unroll
            for (int k = 0; k < 8; k++) {
                float e = (float)ev[k];
                svp[c][k] += e * ri;
                p += e * ci[c][k];
            }
        }
        p += __shfl_xor(p, 1);  p += __shfl_xor(p, 2);  p += __shfl_xor(p, 4);
        p += __shfl_xor(p, 8);  p += __shfl_xor(p, 16); p += __shfl_xor(p, 32);
        if (lane == 0) sq[b * NQ + q0 + q] = p;
    }
    #pragma unroll
    for (int c = 0; c < 2; c++)
        #pragma unroll
        for (int k = 0; k < 8; k++)
            atomicAdd(&sv[b * NV + c * 512 + lane * 8 + k], svp[c][k]);
}

// v_hat[b,d] += sum_{v chunk} sv[b,v] * V[b,v,d]  — float2/lane (8 B)
__global__ __launch_bounds__(256) void vhat_k(const float* __restrict__ sv,
                                              const float* __restrict__ V,
                                              float* __restrict__ out) {
    const int b  = blockIdx.y;
    const int v0 = blockIdx.x * 128;
    const int t  = threadIdx.x;               // 256 threads * float2 = 512 cols
    const float* Vb  = V + ((size_t)b * NV + v0) * VD + t * 2;
    const float* svb = sv + b * NV + v0;
    float ax = 0.f, ay = 0.f;
    #pragma unroll 8
    for (int v = 0; v < 128; v++) {
        const float s = svb[v];
        const float2 val = *(const float2*)(Vb + (size_t)v * VD);
        ax += s * val.x; ay += s * val.y;
    }
    atomicAdd(&out[b * VD + t * 2],     ax);
    atomicAdd(&out[b * VD + t * 2 + 1], ay);
}

// q_hat[b,d] += sum_{q chunk} sq[b,q] * Q[b,q,d]  (out pre-offset), 384 thr
__global__ __launch_bounds__(384) void qhat_k(const float* __restrict__ sq,
                                              const float* __restrict__ Q,
                                              float* __restrict__ out) {
    const int b  = blockIdx.y;
    const int q0 = blockIdx.x * 64;
    const int t  = threadIdx.x;               // 384 threads * float2 = 768 cols
    const float* Qb  = Q + ((size_t)b * NQ + q0) * QD + t * 2;
    const float* sqb = sq + b * NQ + q0;
    float ax = 0.f, ay = 0.f;
    #pragma unroll 8
    for (int q = 0; q < 64; q++) {
        const float s = sqb[q];
        const float2 val = *(const float2*)(Qb + (size_t)q * QD);
        ax += s * val.x; ay += s * val.y;
    }
    atomicAdd(&out[b * QD + t * 2],     ax);
    atomicAdd(&out[b * QD + t * 2 + 1], ay);
}

// ---------------------------------------------------------------------------
extern "C" void kernel_launch(void* const* d_in, const int* in_sizes, int n_in,
                              void* d_out, int out_size, void* d_ws, size_t ws_size,
                              hipStream_t stream) {
    const float* V    = (const float*)d_in[0];
    const float* Q    = (const float*)d_in[1];
    const float* Wq_w = (const float*)d_in[2];
    const float* Wq_b = (const float*)d_in[3];
    const float* Wv_w = (const float*)d_in[4];
    const float* Wv_b = (const float*)d_in[5];
    float* out = (float*)d_out;

    const size_t nQp = (size_t)B_SZ * NQ * HIDD;
    const size_t nVp = (size_t)B_SZ * NV * HIDD;
    const size_t nE  = (size_t)B_SZ * NQ * NV;
    const size_t nWq = (size_t)HIDD * QD;
    const size_t nWv = (size_t)HIDD * VD;
    __bf16* Qp = (__bf16*)d_ws;
    __bf16* Vp = Qp + nQp;
    __bf16* E  = Vp + nVp;
    float* R   = (float*)(E + nE);                 // B*NQ
    float* C   = R + (size_t)B_SZ * NQ;            // B*NV
    float* sv  = C + (size_t)B_SZ * NV;            // B*NV
    float* sq  = sv + (size_t)B_SZ * NV;           // B*NQ
    __bf16* Wq = (__bf16*)(sq + (size_t)B_SZ * NQ);
    __bf16* Wv = Wq + nWq;
    size_t need = (nQp + nVp + nE + nWq + nWv) * 2 +
                  ((size_t)B_SZ * (NQ + NV) * 2) * 4;
    if (ws_size < need) return;

    hipMemsetAsync(R, 0, (size_t)B_SZ * (NQ + NV) * 2 * sizeof(float), stream);
    hipMemsetAsync(d_out, 0, (size_t)out_size * sizeof(float), stream);

    cvt2_k<<<(int)((nWq + nWv) / 1024), 256, 0, stream>>>(
        Wq_w, Wv_w, Wq, (int)(nWq / 4), (int)((nWq + nWv) / 4));

    proj_k<<<(B_SZ * NQ) / 64 + (B_SZ * NV) / 64, 256, 0, stream>>>(
        Q, V, Wq, Wv, Wq_b, Wv_b, Qp, Vp);

    gemm_h<<<dim3(NV / 256, NQ / 128, B_SZ), 256, 0, stream>>>(Qp, Vp, E, R, C);

    marg_k<<<dim3(NQ / 16, B_SZ), 256, 0, stream>>>(E, R, C, sv, sq);

    vhat_k<<<dim3(NV / 128, B_SZ), 256, 0, stream>>>(sv, V, out);
    qhat_k<<<dim3(NQ / 64, B_SZ), 384, 0, stream>>>(sq, Q, out + (size_t)B_SZ * VD);
}

// Round 2
// 461.801 us; speedup vs baseline: 1.4351x; 1.4351x over previous
//
#include <hip/hip_runtime.h>
#include <hip/hip_bf16.h>
#include <math.h>

#define B_SZ 64
#define NQ   512
#define NV   1024
#define QD   768
#define VD   512
#define HIDD 512

typedef __bf16 bf16x8 __attribute__((ext_vector_type(8)));
typedef __bf16 bf16x4 __attribute__((ext_vector_type(4)));
typedef float  floatx4 __attribute__((ext_vector_type(4)));

// async global->LDS, 16 bytes per lane; LDS dest is wave-uniform base,
// HW writes lane l at base + l*16 (linear). Swizzle must be applied on the
// global SOURCE address + the LDS READ (both-sides-or-neither).
__device__ __forceinline__ void g2lds16(const __bf16* g, __bf16* l) {
    __builtin_amdgcn_global_load_lds((const __attribute__((address_space(1))) void*)g,
                                     (__attribute__((address_space(3))) void*)l,
                                     16, 0, 0);
}

// exp(tanh(s)) = e^(1 - 2/(e^{2s}+1)); saturates correctly as e^{2s}->0/inf.
__device__ __forceinline__ float exptanh(float s) {
    float t = __expf(2.0f * s);
    float r = __builtin_amdgcn_rcpf(t + 1.0f);
    return __expf(1.0f - 2.0f * r);
}

// ---------------------------------------------------------------------------
// fp32 -> bf16 convert for both weight matrices in one launch (dests adjacent).
__global__ __launch_bounds__(256) void cvt2_k(const float* __restrict__ s0,
                                              const float* __restrict__ s1,
                                              __bf16* __restrict__ d,
                                              int n4a, int n4tot) {
    int i = blockIdx.x * 256 + threadIdx.x;
    if (i >= n4tot) return;
    const float* s = (i < n4a) ? (s0 + (size_t)i * 4) : (s1 + (size_t)(i - n4a) * 4);
    float4 f = *(const float4*)s;
    bf16x4 o;
    o[0] = (__bf16)f.x; o[1] = (__bf16)f.y; o[2] = (__bf16)f.z; o[3] = (__bf16)f.w;
    *(bf16x4*)(d + (size_t)i * 4) = o;
}

// ---------------------------------------------------------------------------
// Projection GEMM, Q and V fused into one dispatch (blocks < nqblk do Q).
// Block = 64 rows x ALL 512 cols (A read from HBM exactly once). 4 waves,
// each 64x128 (acc 4x8). Double-buffered LDS, 2-phase schedule.
__global__ __launch_bounds__(256, 2) void proj_k(
    const float* __restrict__ Qin, const float* __restrict__ Vin,
    const __bf16* __restrict__ Wqb, const __bf16* __restrict__ Wvb,
    const float* __restrict__ bq, const float* __restrict__ bv,
    __bf16* __restrict__ Qp, __bf16* __restrict__ Vp)
{
    __shared__ __bf16 As[2][64 * 32];    // 8 KB
    __shared__ __bf16 Bs[2][512 * 32];   // 64 KB
    const int nqblk = (B_SZ * NQ) / 64;
    const float* A; const __bf16* W; const float* bias; __bf16* Cout; int K, mblk;
    if ((int)blockIdx.x < nqblk) {
        A = Qin; W = Wqb; bias = bq; Cout = Qp; K = QD; mblk = blockIdx.x;
    } else {
        A = Vin; W = Wvb; bias = bv; Cout = Vp; K = VD; mblk = blockIdx.x - nqblk;
    }

    const int t = threadIdx.x, lane = t & 63, wave = t >> 6;
    const int fr = lane & 15, quad = lane >> 4;
    const int fo   = (quad ^ ((fr >> 1) & 3)) * 8;            // swizzled frag read
    const int gksw = ((lane & 3) ^ ((lane >> 3) & 3)) * 8;    // pre-swizzled g2lds src col
    const int tile_m = mblk * 64;
    const int wn = wave * 128;

    const __bf16* wsrc = W + (size_t)(wave * 16 + (lane >> 2)) * K + gksw;
    const int arow = t >> 2, aslot = t & 3;
    const float* ap = A + (size_t)(tile_m + arow) * K + aslot * 8;
    const int awoff = arow * 32 + ((aslot ^ ((arow >> 1) & 3)) * 8);  // swizzled write

    floatx4 acc[4][8] = {};

    auto stage_w = [&](int p, int k0) {
        #pragma unroll
        for (int c = 0; c < 8; c++)
            g2lds16(wsrc + (size_t)(c * 64) * K + k0, &Bs[p][(c * 64 + wave * 16) * 32]);
    };
    auto cvt_a = [&](int p, float4 f0, float4 f1) {
        bf16x8 pk;
        pk[0] = (__bf16)f0.x; pk[1] = (__bf16)f0.y; pk[2] = (__bf16)f0.z; pk[3] = (__bf16)f0.w;
        pk[4] = (__bf16)f1.x; pk[5] = (__bf16)f1.y; pk[6] = (__bf16)f1.z; pk[7] = (__bf16)f1.w;
        *(bf16x8*)&As[p][awoff] = pk;
    };
    auto compute = [&](int p) {
        bf16x8 af[4];
        #pragma unroll
        for (int i = 0; i < 4; i++)
            af[i] = *(const bf16x8*)&As[p][(16 * i + fr) * 32 + fo];
        #pragma unroll
        for (int j = 0; j < 8; j++) {
            bf16x8 bg = *(const bf16x8*)&Bs[p][(wn + 16 * j + fr) * 32 + fo];
            #pragma unroll
            for (int i = 0; i < 4; i++)
                acc[i][j] = __builtin_amdgcn_mfma_f32_16x16x32_bf16(af[i], bg, acc[i][j], 0, 0, 0);
        }
    };

    {
        float4 f0 = *(const float4*)(ap);
        float4 f1 = *(const float4*)(ap + 4);
        stage_w(0, 0);
        cvt_a(0, f0, f1);
    }
    __syncthreads();
    int cur = 0;
    for (int k0 = 32; k0 < K; k0 += 32) {
        float4 f0 = *(const float4*)(ap + k0);
        float4 f1 = *(const float4*)(ap + k0 + 4);
        const int nxt = cur ^ 1;
        stage_w(nxt, k0);
        compute(cur);
        cvt_a(nxt, f0, f1);
        __syncthreads();
        cur = nxt;
    }
    compute(cur);

    #pragma unroll
    for (int j = 0; j < 8; j++) {
        const int col = wn + 16 * j + fr;
        const float bvv = bias[col];
        #pragma unroll
        for (int i = 0; i < 4; i++)
            #pragma unroll
            for (int r = 0; r < 4; r++) {
                const int row = tile_m + 16 * i + quad * 4 + r;
                Cout[(size_t)row * HIDD + col] = (__bf16)(acc[i][j][r] + bvv);
            }
    }
}

// ---------------------------------------------------------------------------
// Per batch: S = Qp[b] @ Vp[b]^T on a 128x256 tile; E = exp(tanh(S)) -> bf16;
// row sums -> R, col sums -> C (atomics).
__global__ __launch_bounds__(256, 2) void gemm_h(
    const __bf16* __restrict__ Qp, const __bf16* __restrict__ Vp,
    __bf16* __restrict__ Eg, float* __restrict__ R, float* __restrict__ Csum)
{
    __shared__ __bf16 As[2][128 * 32];   // 16 KB
    __shared__ __bf16 Bs[2][256 * 32];   // 32 KB
    const int b      = blockIdx.z;
    const int tile_q = blockIdx.y * 128;
    const int tile_v = blockIdx.x * 256;
    const int t = threadIdx.x, lane = t & 63, wave = t >> 6;
    const int fr = lane & 15, quad = lane >> 4;
    const int fo   = (quad ^ ((fr >> 1) & 3)) * 8;
    const int gksw = ((lane & 3) ^ ((lane >> 3) & 3)) * 8;
    const int wm = (wave >> 1) * 64, wn = (wave & 1) * 128;

    const __bf16* Aq = Qp + ((size_t)b * NQ + tile_q + wave * 16 + (lane >> 2)) * HIDD + gksw;
    const __bf16* Bv = Vp + ((size_t)b * NV + tile_v + wave * 16 + (lane >> 2)) * HIDD + gksw;

    auto stage = [&](int p, int k0) {
        #pragma unroll
        for (int c = 0; c < 2; c++)
            g2lds16(Aq + (size_t)(c * 64) * HIDD + k0, &As[p][(c * 64 + wave * 16) * 32]);
        #pragma unroll
        for (int c = 0; c < 4; c++)
            g2lds16(Bv + (size_t)(c * 64) * HIDD + k0, &Bs[p][(c * 64 + wave * 16) * 32]);
    };

    floatx4 acc[4][8] = {};
    auto compute = [&](int p) {
        bf16x8 af[4];
        #pragma unroll
        for (int i = 0; i < 4; i++)
            af[i] = *(const bf16x8*)&As[p][(wm + 16 * i + fr) * 32 + fo];
        #pragma unroll
        for (int j = 0; j < 8; j++) {
            bf16x8 bg = *(const bf16x8*)&Bs[p][(wn + 16 * j + fr) * 32 + fo];
            #pragma unroll
            for (int i = 0; i < 4; i++)
                acc[i][j] = __builtin_amdgcn_mfma_f32_16x16x32_bf16(af[i], bg, acc[i][j], 0, 0, 0);
        }
    };

    stage(0, 0);
    __syncthreads();
    int cur = 0;
    for (int k0 = 32; k0 < HIDD; k0 += 32) {
        stage(cur ^ 1, k0);
        compute(cur);
        __syncthreads();
        cur ^= 1;
    }
    compute(cur);

    #pragma unroll
    for (int i = 0; i < 4; i++)
        #pragma unroll
        for (int j = 0; j < 8; j++)
            #pragma unroll
            for (int r = 0; r < 4; r++)
                acc[i][j][r] = exptanh(acc[i][j][r]);

    #pragma unroll
    for (int i = 0; i < 4; i++)
        #pragma unroll
        for (int r = 0; r < 4; r++) {
            const size_t rowbase =
                ((size_t)b * NQ + tile_q + wm + 16 * i + quad * 4 + r) * NV + tile_v;
            #pragma unroll
            for (int j = 0; j < 8; j++)
                Eg[rowbase + wn + 16 * j + fr] = (__bf16)acc[i][j][r];
        }

    #pragma unroll
    for (int i = 0; i < 4; i++)
        #pragma unroll
        for (int r = 0; r < 4; r++) {
            float s = 0.f;
            #pragma unroll
            for (int j = 0; j < 8; j++) s += acc[i][j][r];
            s += __shfl_xor(s, 1); s += __shfl_xor(s, 2);
            s += __shfl_xor(s, 4); s += __shfl_xor(s, 8);
            if (fr == 0)
                atomicAdd(&R[b * NQ + tile_q + wm + 16 * i + quad * 4 + r], s);
        }
    #pragma unroll
    for (int j = 0; j < 8; j++) {
        float s = 0.f;
        #pragma unroll
        for (int i = 0; i < 4; i++)
            #pragma unroll
            for (int r = 0; r < 4; r++) s += acc[i][j][r];
        s += __shfl_xor(s, 16); s += __shfl_xor(s, 32);
        if (quad == 0)
            atomicAdd(&Csum[b * NV + tile_v + wn + 16 * j + fr], s);
    }
}

// ---------------------------------------------------------------------------
// One E pass computes both marginals:
//   sv[b,v] = sum_q E[b,q,v]/R[b,q]   (LDS cross-wave reduce -> 1 atomic/(blk,v))
//   sq[b,q] = sum_v E[b,q,v]/C[b,v]   (wave-exclusive rows, direct write)
// 512 threads (8 waves), 8 rows/wave, qsplit=8 -> 16 waves/CU of TLP.
__global__ __launch_bounds__(512) void marg_k(
    const __bf16* __restrict__ E, const float* __restrict__ R,
    const float* __restrict__ C, float* __restrict__ sv,
    float* __restrict__ sq)
{
    __shared__ float sred[8][1024];   // 32 KB
    const int b  = blockIdx.y;
    const int q0 = blockIdx.x * 64;
    const int t = threadIdx.x, lane = t & 63, wave = t >> 6;
    const float* Cb = C + b * NV;
    float ci[2][8];
    float svp[2][8] = {};
    #pragma unroll
    for (int c = 0; c < 2; c++) {
        float4 c0 = *(const float4*)&Cb[c * 512 + lane * 8];
        float4 c1 = *(const float4*)&Cb[c * 512 + lane * 8 + 4];
        ci[c][0] = 1.0f / c0.x; ci[c][1] = 1.0f / c0.y;
        ci[c][2] = 1.0f / c0.z; ci[c][3] = 1.0f / c0.w;
        ci[c][4] = 1.0f / c1.x; ci[c][5] = 1.0f / c1.y;
        ci[c][6] = 1.0f / c1.z; ci[c][7] = 1.0f / c1.w;
    }
    const float* Rb = R + b * NQ + q0 + wave * 8;
    const __bf16* Ebase = E + ((size_t)b * NQ + q0 + wave * 8) * NV;
    #pragma unroll
    for (int rr = 0; rr < 8; rr++) {
        const __bf16* Erow = Ebase + (size_t)rr * NV;
        const float ri = 1.0f / Rb[rr];
        float p = 0.f;
        #pragma unroll
        for (int c = 0; c < 2; c++) {
            bf16x8 ev = *(const bf16x8*)&Erow[c * 512 + lane * 8];
            #pragma unroll
            for (int k = 0; k < 8; k++) {
                float e = (float)ev[k];
                svp[c][k] += e * ri;
                p += e * ci[c][k];
            }
        }
        p += __shfl_xor(p, 1);  p += __shfl_xor(p, 2);  p += __shfl_xor(p, 4);
        p += __shfl_xor(p, 8);  p += __shfl_xor(p, 16); p += __shfl_xor(p, 32);
        if (lane == 0) sq[b * NQ + q0 + wave * 8 + rr] = p;
    }
    // per-wave partials -> LDS
    #pragma unroll
    for (int c = 0; c < 2; c++) {
        float4 w0 = { svp[c][0], svp[c][1], svp[c][2], svp[c][3] };
        float4 w1 = { svp[c][4], svp[c][5], svp[c][6], svp[c][7] };
        *(float4*)&sred[wave][c * 512 + lane * 8]     = w0;
        *(float4*)&sred[wave][c * 512 + lane * 8 + 4] = w1;
    }
    __syncthreads();
    // cross-wave reduce: each thread owns 2 v-entries -> one atomic each
    const int v = t * 2;
    float s0 = 0.f, s1 = 0.f;
    #pragma unroll
    for (int w = 0; w < 8; w++) { s0 += sred[w][v]; s1 += sred[w][v + 1]; }
    atomicAdd(&sv[b * NV + v],     s0);
    atomicAdd(&sv[b * NV + v + 1], s1);
}

// ---------------------------------------------------------------------------
// v_hat partials: vh_part[vs][b][d] = sum_{v in chunk} sv[b,v] * V[b,v,d]
// 512 thr = 4 groups x 128; float4 loads (16 B/lane); sv staged in LDS;
// cross-group LDS reduce; plain stores (no atomics).
__global__ __launch_bounds__(512) void vhat_k(const float* __restrict__ sv,
                                              const float* __restrict__ V,
                                              float* __restrict__ vh_part) {
    __shared__ float svl[256];
    __shared__ float4 red[4][128];
    const int b  = blockIdx.y;
    const int v0 = blockIdx.x * 256;
    const int t  = threadIdx.x;
    if (t < 256) svl[t] = sv[b * NV + v0 + t];
    __syncthreads();
    const int g = t >> 7, gi = t & 127;
    const float* Vb = V + ((size_t)b * NV + v0 + g) * VD + gi * 4;
    float4 a = {0.f, 0.f, 0.f, 0.f};
    #pragma unroll 8
    for (int i = 0; i < 64; i++) {
        const float s = svl[g + 4 * i];
        const float4 x = *(const float4*)(Vb + (size_t)(4 * i) * VD);
        a.x += s * x.x; a.y += s * x.y; a.z += s * x.z; a.w += s * x.w;
    }
    red[g][gi] = a;
    __syncthreads();
    if (t < 128) {
        float4 r0 = red[0][t], r1 = red[1][t], r2 = red[2][t], r3 = red[3][t];
        float4 o;
        o.x = r0.x + r1.x + r2.x + r3.x;
        o.y = r0.y + r1.y + r2.y + r3.y;
        o.z = r0.z + r1.z + r2.z + r3.z;
        o.w = r0.w + r1.w + r2.w + r3.w;
        *(float4*)&vh_part[((size_t)blockIdx.x * B_SZ + b) * VD + t * 4] = o;
    }
}

// q_hat partials: qh_part[qs][b][d] = sum_{q in chunk} sq[b,q] * Q[b,q,d]
// 384 thr = 2 groups x 192; float4 loads; sq staged in LDS.
__global__ __launch_bounds__(384) void qhat_k(const float* __restrict__ sq,
                                              const float* __restrict__ Q,
                                              float* __restrict__ qh_part) {
    __shared__ float sql[128];
    __shared__ float4 red[2][192];
    const int b  = blockIdx.y;
    const int q0 = blockIdx.x * 128;
    const int t  = threadIdx.x;
    if (t < 128) sql[t] = sq[b * NQ + q0 + t];
    __syncthreads();
    const int g = (t >= 192) ? 1 : 0, gi = t - g * 192;
    const float* Qb = Q + ((size_t)b * NQ + q0 + g) * QD + gi * 4;
    float4 a = {0.f, 0.f, 0.f, 0.f};
    #pragma unroll 8
    for (int i = 0; i < 64; i++) {
        const float s = sql[g + 2 * i];
        const float4 x = *(const float4*)(Qb + (size_t)(2 * i) * QD);
        a.x += s * x.x; a.y += s * x.y; a.z += s * x.z; a.w += s * x.w;
    }
    red[g][gi] = a;
    __syncthreads();
    if (t < 192) {
        float4 r0 = red[0][t], r1 = red[1][t];
        float4 o;
        o.x = r0.x + r1.x; o.y = r0.y + r1.y;
        o.z = r0.z + r1.z; o.w = r0.w + r1.w;
        *(float4*)&qh_part[((size_t)blockIdx.x * B_SZ + b) * QD + t * 4] = o;
    }
}

// combine partials -> out (writes every element; no out memset needed)
__global__ __launch_bounds__(256) void fin_k(const float* __restrict__ vh_part,
                                             const float* __restrict__ qh_part,
                                             float* __restrict__ out) {
    const int i = blockIdx.x * 256 + threadIdx.x;
    const int nv = B_SZ * VD;
    const int nq = B_SZ * QD;
    if (i < nv) {
        float s = 0.f;
        #pragma unroll
        for (int p = 0; p < 4; p++) s += vh_part[(size_t)p * nv + i];
        out[i] = s;
    } else if (i < nv + nq) {
        const int j = i - nv;
        float s = 0.f;
        #pragma unroll
        for (int p = 0; p < 4; p++) s += qh_part[(size_t)p * nq + j];
        out[i] = s;
    }
}

// ---------------------------------------------------------------------------
extern "C" void kernel_launch(void* const* d_in, const int* in_sizes, int n_in,
                              void* d_out, int out_size, void* d_ws, size_t ws_size,
                              hipStream_t stream) {
    const float* V    = (const float*)d_in[0];
    const float* Q    = (const float*)d_in[1];
    const float* Wq_w = (const float*)d_in[2];
    const float* Wq_b = (const float*)d_in[3];
    const float* Wv_w = (const float*)d_in[4];
    const float* Wv_b = (const float*)d_in[5];
    float* out = (float*)d_out;

    const size_t nQp = (size_t)B_SZ * NQ * HIDD;
    const size_t nVp = (size_t)B_SZ * NV * HIDD;
    const size_t nE  = (size_t)B_SZ * NQ * NV;
    const size_t nWq = (size_t)HIDD * QD;
    const size_t nWv = (size_t)HIDD * VD;
    __bf16* Qp = (__bf16*)d_ws;
    __bf16* Vp = Qp + nQp;
    __bf16* E  = Vp + nVp;
    float* R   = (float*)(E + nE);                 // B*NQ
    float* C   = R + (size_t)B_SZ * NQ;            // B*NV
    float* sv  = C + (size_t)B_SZ * NV;            // B*NV
    float* sq  = sv + (size_t)B_SZ * NV;           // B*NQ
    // weights live here during cvt+proj; vh_part/qh_part alias the same
    // region afterwards (weights are dead once proj_k completes).
    __bf16* Wq = (__bf16*)(sq + (size_t)B_SZ * NQ);
    __bf16* Wv = Wq + nWq;
    float* vh_part = (float*)Wq;                        // [4][B][VD] = 512 KB
    float* qh_part = vh_part + (size_t)4 * B_SZ * VD;   // [4][B][QD] = 768 KB
    size_t need = (nQp + nVp + nE + nWq + nWv) * 2 +
                  ((size_t)B_SZ * (NQ + NV) * 2) * 4;
    if (ws_size < need) return;

    // zero R, C, sv (contiguous); sq/out fully overwritten, no memset
    hipMemsetAsync(R, 0, ((size_t)B_SZ * (NQ + 2 * NV)) * sizeof(float), stream);

    cvt2_k<<<(int)((nWq + nWv) / 1024), 256, 0, stream>>>(
        Wq_w, Wv_w, Wq, (int)(nWq / 4), (int)((nWq + nWv) / 4));

    proj_k<<<(B_SZ * NQ) / 64 + (B_SZ * NV) / 64, 256, 0, stream>>>(
        Q, V, Wq, Wv, Wq_b, Wv_b, Qp, Vp);

    gemm_h<<<dim3(NV / 256, NQ / 128, B_SZ), 256, 0, stream>>>(Qp, Vp, E, R, C);

    marg_k<<<dim3(NQ / 64, B_SZ), 512, 0, stream>>>(E, R, C, sv, sq);

    vhat_k<<<dim3(NV / 256, B_SZ), 512, 0, stream>>>(sv, V, vh_part);
    qhat_k<<<dim3(NQ / 128, B_SZ), 384, 0, stream>>>(sq, Q, qh_part);

    fin_k<<<(B_SZ * (VD + QD) + 255) / 256, 256, 0, stream>>>(vh_part, qh_part, out);
}